// Round 23
// baseline (120.796 us; speedup 1.0000x reference)
//
#include <hip/hip_runtime.h>
#include <hip/hip_bf16.h>

#define NB 2
#define NT 2048
#define ND 1024
#define NH 16
#define NDK 64

typedef __attribute__((ext_vector_type(8))) short bf16x8;
typedef __attribute__((ext_vector_type(4))) float f32x4;

#define VMCNT0 asm volatile("s_waitcnt vmcnt(0)" ::: "memory")
#define VMCNT3 asm volatile("s_waitcnt vmcnt(3)" ::: "memory")

static __device__ __forceinline__ short f2bf(float f) {
  union { float f; unsigned u; } c; c.f = f;
  unsigned u = c.u;
  u += 0x7FFF + ((u >> 16) & 1);   // round-to-nearest-even
  return (short)(u >> 16);
}

// packed RNE f32x2 -> bf16x2 (1 instr)
static __device__ __forceinline__ unsigned cvt_pk_bf16(float lo, float hi) {
  unsigned r;
  asm("v_cvt_pk_bf16_f32 %0, %1, %2" : "=v"(r) : "v"(lo), "v"(hi));
  return r;
}

static __device__ __forceinline__ void gload16(const void* g, void* l) {
  __builtin_amdgcn_global_load_lds((const __attribute__((address_space(1))) void*)g,
                                   (__attribute__((address_space(3))) void*)l, 16, 0, 0);
}

// ---------------- prep: fp32->bf16 cast (3 tensors) + weight transpose (4), one launch ----
__global__ void prep_kernel(const float* __restrict__ Q, const float* __restrict__ Ki,
                            const float* __restrict__ V,
                            short* __restrict__ Qb, short* __restrict__ Kb, short* __restrict__ Vb,
                            const float* __restrict__ W0, const float* __restrict__ W1,
                            const float* __restrict__ W2, const float* __restrict__ W3,
                            short* __restrict__ T0, short* __restrict__ T1,
                            short* __restrict__ T2, short* __restrict__ T3) {
  __shared__ float t[32][33];
  int d = blockIdx.x, tid = threadIdx.x;
  if (d < 6144) {                             // cast part: 2048 blocks per tensor
    int z = d >> 11;
    int i = (d & 2047) * 256 + tid;
    const float* src = z == 0 ? Q : (z == 1 ? Ki : V);
    short* dst       = z == 0 ? Qb : (z == 1 ? Kb : Vb);
    const float4* s4 = (const float4*)src + (size_t)i * 2;
    float4 a = s4[0], b = s4[1];
    bf16x8 o;
    o[0] = f2bf(a.x); o[1] = f2bf(a.y); o[2] = f2bf(a.z); o[3] = f2bf(a.w);
    o[4] = f2bf(b.x); o[5] = f2bf(b.y); o[6] = f2bf(b.z); o[7] = f2bf(b.w);
    *((bf16x8*)dst + i) = o;
  } else {                                    // wtrans part: 1024 blocks per weight
    int dd = d - 6144;
    int z = dd >> 10;
    int rem = dd & 1023;
    const float* W = z == 0 ? W0 : (z == 1 ? W1 : (z == 2 ? W2 : W3));
    short* Wt      = z == 0 ? T0 : (z == 1 ? T1 : (z == 2 ? T2 : T3));
    int n0 = (rem & 31) * 32, k0 = (rem >> 5) * 32;
    int tx = tid & 31, ty = tid >> 5;         // (32,8)
    for (int i = ty; i < 32; i += 8) t[i][tx] = W[(size_t)(k0 + i) * ND + n0 + tx];
    __syncthreads();
    for (int i = ty; i < 32; i += 8) Wt[(size_t)(n0 + i) * ND + k0 + tx] = f2bf(t[tx][i]);
  }
}

// ---------------- GEMM: C[M,N] = A[M,K] * Wt[N,K]^T + bias ----------------
// BMxBN tile, BK=32, 4 waves, 16x16x32 bf16 MFMA. Triple-buffered LDS with
// counted vmcnt (3 loads/thread/stage -> VMCNT3) + raw s_barrier. 1D grid with
// XCD-aware swizzle. LDS-transpose epilogue for vector stores.
// MODE 0 (BM=64, BN=128, 1536 blocks): round-22 lever -- the old BM=128 grid
//   (768 = exactly 3 blocks/CU) was the occupancy cap for a latency-bound
//   K-loop; BM=64 gives 1536 blocks, 36KB LDS -> 4 resident blocks/CU (16
//   waves/CU) + backfill, and a shorter per-K-step chain (6 ds_read + 8 MFMA).
//   z=0 -> q (PRE-SCALED by 0.125*log2e) [B,H,T,DK];
//   z=1 -> k fragment order [bh][t>>4][dk>>3][t&15][dk&7];
//   z=2 -> V^T fragment order [bh][dk>>4][t>>3][dk&15][t&7].
// MODE 1 (BM=128, BN=64, 512 blocks): fp32 out [M,N] (unchanged geometry).
template <int MODE>
__global__ __launch_bounds__(256, 3) void gemm_bt(
    const short* __restrict__ A0, const short* __restrict__ A1, const short* __restrict__ A2,
    const short* __restrict__ W0, const short* __restrict__ W1, const short* __restrict__ W2,
    const float* __restrict__ b0, const float* __restrict__ b1, const float* __restrict__ b2,
    void* o0, void* o1, void* o2)
{
  constexpr int K = ND;
  constexpr int NK = K / 32;
  constexpr int BM = (MODE == 0) ? 64 : 128;
  constexpr int BN = (MODE == 0) ? 128 : 64;
  constexpr int NMB = (NB * NT) / BM;        // m-blocks
  constexpr int NNB = ND / BN;               // n-blocks
  constexpr int NZ = (MODE == 0) ? 3 : 1;
  constexpr int NWPX = NZ * NMB * NNB / 8;
  __shared__ short As[3][BM * 32];
  __shared__ short Bs[3][BN * 32];

  int d = blockIdx.x;
  int work = (d & 7) * NWPX + (d >> 3);      // XCD-contiguous work chunks
  int z = work / (NMB * NNB);
  int rem = work % (NMB * NNB);
  int m0 = (rem / NNB) * BM, n0 = (rem % NNB) * BN;

  const short* A    = z == 0 ? A0 : (z == 1 ? A1 : A2);
  const short* Wt   = z == 0 ? W0 : (z == 1 ? W1 : W2);
  const float* bias = z == 0 ? b0 : (z == 1 ? b1 : b2);
  void* out         = z == 0 ? o0 : (z == 1 ? o1 : o2);
  float scl = (MODE == 0 && z == 0) ? 0.18033688011112042f : 1.0f;

  int tid = threadIdx.x, wid = tid >> 6, lane = tid & 63;
  int wr = (BM == 128) ? (wid >> 1) : 0;     // wave row-group (64 rows each)
  int wc = (BM == 128) ? (wid & 1) : wid;    // wave col-group (32 cols each)
  int r16 = lane & 15, l4 = lane >> 4;

  auto stage = [&](int buf, int kt) {
    int row = tid >> 2;                      // 0..63
    int c8 = (tid & 3) * 8;
#pragma unroll
    for (int c = 0; c < BM / 64; c++)
      gload16(A + (size_t)(m0 + c * 64 + row) * K + kt * 32 + c8,
              &As[buf][c * 2048 + tid * 8]);
#pragma unroll
    for (int c = 0; c < BN / 64; c++)
      gload16(Wt + (size_t)(n0 + c * 64 + row) * K + kt * 32 + c8,
              &Bs[buf][c * 2048 + tid * 8]);
  };

  f32x4 acc[4][2] = {};
  stage(0, 0);
  stage(1, 1);

  int cur = 0;
  for (int kt = 0; kt < NK; ++kt) {
    // drain only the oldest stage (tile kt); keep tile kt+1's loads in flight
    if (kt + 1 < NK) { VMCNT3; } else { VMCNT0; }
    __builtin_amdgcn_s_barrier();            // raw: no compiler vmcnt(0) drain
    if (kt + 2 < NK) {
      int nb_ = cur + 2; if (nb_ >= 3) nb_ -= 3;
      stage(nb_, kt + 2);                    // overwrites buffer computed at kt-1
    }
    bf16x8 af[4], bfv[2];
    int kk = l4 * 8;
#pragma unroll
    for (int mi = 0; mi < 4; mi++)
      af[mi] = *(const bf16x8*)&As[cur][(wr * 64 + mi * 16 + r16) * 32 + kk];
#pragma unroll
    for (int ni = 0; ni < 2; ni++)
      bfv[ni] = *(const bf16x8*)&Bs[cur][(wc * 32 + ni * 16 + r16) * 32 + kk];
#pragma unroll
    for (int mi = 0; mi < 4; mi++)
#pragma unroll
      for (int ni = 0; ni < 2; ni++)
        acc[mi][ni] = __builtin_amdgcn_mfma_f32_16x16x32_bf16(af[mi], bfv[ni], acc[mi][ni], 0, 0, 0);
    cur = cur + 1; if (cur >= 3) cur = 0;
  }

  int mb = m0 + wr * 64, nb = n0 + wc * 32;

  if constexpr (MODE == 0) {
    if (z == 2) {
      // V^T fragment layout (vectorizable per-thread): direct short4 path
#pragma unroll
      for (int mi = 0; mi < 4; mi++)
#pragma unroll
        for (int ni = 0; ni < 2; ni++) {
          int n = nb + ni * 16 + r16;
          float bv = bias[n];
          int h = n >> 6, dk = n & 63;
          int m0_ = mb + mi * 16 + l4 * 4;
          int bI = m0_ >> 11, t0 = m0_ & (NT - 1);
          int bh = bI * NH + h;
          short4 s4;
          s4.x = f2bf(acc[mi][ni][0] + bv);
          s4.y = f2bf(acc[mi][ni][1] + bv);
          s4.z = f2bf(acc[mi][ni][2] + bv);
          s4.w = f2bf(acc[mi][ni][3] + bv);
          *(short4*)&((short*)out)[(size_t)bh * 131072 + (dk >> 4) * 32768 +
                                   (t0 >> 3) * 128 + (dk & 15) * 8 + (t0 & 7)] = s4;
        }
      return;
    }
  }

  // ---- LDS-transpose epilogue (z=0, z=1, MODE1): thread ends with row m,
  //      4 consecutive n -> vector stores ----
  __syncthreads();                           // all ds_reads of As done; reuse as scratch
  float* scr = (float*)&As[0][0] + wid * 320;  // per-wave [16][20] f32 (5KB total, fits)
#pragma unroll
  for (int mi = 0; mi < 4; mi++)
#pragma unroll
    for (int ni = 0; ni < 2; ni++) {
#pragma unroll
      for (int r = 0; r < 4; r++)
        scr[(l4 * 4 + r) * 20 + r16] = acc[mi][ni][r];
      float4 tv = *(float4*)&scr[r16 * 20 + l4 * 4];
      int n0q = nb + ni * 16 + l4 * 4;       // 4 consecutive n, multiple of 4
      float4 bv4 = *(const float4*)&bias[n0q];
      float v0 = tv.x + bv4.x, v1 = tv.y + bv4.y;
      float v2 = tv.z + bv4.z, v3 = tv.w + bv4.w;
      int m = mb + mi * 16 + r16;
      if constexpr (MODE == 0) {
        int bI = m >> 11, t = m & (NT - 1);
        if (z == 0) {
          int h = n0q >> 6, dk = n0q & 63;
          *(int2*)&((short*)out)[((((size_t)bI * NH + h) * NT + t) << 6) + dk] =
              make_int2((int)cvt_pk_bf16(v0 * scl, v1 * scl),
                        (int)cvt_pk_bf16(v2 * scl, v3 * scl));
        } else {                             // z == 1, fully coalesced int2
          int bh = bI * NH + (n0q >> 6);
          int dk = n0q & 63;
          *(int2*)&((short*)out)[(size_t)bh * 131072 + (t >> 4) * 1024 +
                                 (dk >> 3) * 128 + (t & 15) * 8 + (dk & 7)] =
              make_int2((int)cvt_pk_bf16(v0, v1), (int)cvt_pk_bf16(v2, v3));
        }
      } else {
        *(float4*)&((float*)out)[(size_t)m * ND + n0q] = make_float4(v0, v1, v2, v3);
      }
    }
}

// ---------------- flash attention v11 (best measured: ~40.2 us) ----------
// 2048 blocks x 4 waves, KV-split-4, fragment-contiguous K/V, K rotate-prefetch,
// max-free exp2 softmax, O^T orientation, rf-staggered, two-pass merge.
__global__ __launch_bounds__(256) void attn_kernel(
    const short* __restrict__ q, const short* __restrict__ k, const short* __restrict__ vt,
    short* __restrict__ O)
{
  struct SH {
    union {
      short p2[4][2][16][72];                // per-wave P tile (loop phase), 18432 B
      struct {
        f32x4 obuf[4][2][2][64];             // [wave][rf][dfp][lane], 16384 B
        float ol[4][32];                     // [wave][qrow]
      } mg;                                  // merge phase (two df-passes)
    };
  };
  __shared__ SH sh;

  int d = blockIdx.x;                        // 2048 blocks
  int xcd = d & 7, jj = d >> 3;              // jj in 0..255
  int bh = xcd * 4 + (jj >> 6);              // 4 (b,h) per XCD for L2 locality
  int qg = 63 - (jj & 63);                   // long q-groups dispatch first
  int b = bh >> 4, h = bh & 15;
  int tid = threadIdx.x, wid = tid >> 6, lane = tid & 63;
  int r16 = lane & 15, l4 = lane >> 4;
  size_t hb = (size_t)bh * NT * NDK;
  const short* qh = q + hb;
  const short* kh = k + hb;                  // fragment order [t>>4][dk>>3][t&15][dk&7]
  const short* vh = vt + hb;                 // fragment order [dk>>4][t>>3][dk&15][t&7]
  int qw = qg * 32;                          // this block's 32 q-rows

  // Q fragments (B-operand): same for all 4 waves
  bf16x8 qa[2][2];
#pragma unroll
  for (int rf = 0; rf < 2; rf++)
#pragma unroll
    for (int kf = 0; kf < 2; kf++)
      qa[rf][kf] = *(const bf16x8*)(qh + (size_t)(qw + rf * 16 + r16) * NDK + kf * 32 + l4 * 8);

  f32x4 of[2][4] = {};
  float l0 = 0.f, l1 = 0.f;

  int nt = (qw + 95) >> 6;                   // KV tiles covering kv <= qw+31

  // preload K fragments for this wave's first tile (rotate-register pipeline)
  bf16x8 kfr[4][2];
  if (wid < nt) {
#pragma unroll
    for (int cf = 0; cf < 4; cf++) {
      const short* kb_ = kh + (size_t)((wid * 64 >> 4) + cf) * 1024 + lane * 8;
      kfr[cf][0] = *(const bf16x8*)kb_;
      kfr[cf][1] = *(const bf16x8*)(kb_ + 512);
    }
  }

  for (int kt = wid; kt < nt; kt += 4) {
    int kv0 = kt * 64;
    f32x4 sf[2][4] = {};

    // QK rf=0
#pragma unroll
    for (int cf = 0; cf < 4; cf++) {
      sf[0][cf] = __builtin_amdgcn_mfma_f32_16x16x32_bf16(kfr[cf][0], qa[0][0], sf[0][cf], 0, 0, 0);
      sf[0][cf] = __builtin_amdgcn_mfma_f32_16x16x32_bf16(kfr[cf][1], qa[0][1], sf[0][cf], 0, 0, 0);
    }
    // QK rf=1
#pragma unroll
    for (int cf = 0; cf < 4; cf++) {
      sf[1][cf] = __builtin_amdgcn_mfma_f32_16x16x32_bf16(kfr[cf][0], qa[1][0], sf[1][cf], 0, 0, 0);
      sf[1][cf] = __builtin_amdgcn_mfma_f32_16x16x32_bf16(kfr[cf][1], qa[1][1], sf[1][cf], 0, 0, 0);
    }

    // prefetch K for tile kt+4 into the same registers (clamped past end);
    // latency hides under the softmax/PV below
    {
      int ktn = (kt + 4 < nt) ? kt + 4 : kt;
      int kvn = ktn * 64;
#pragma unroll
      for (int cf = 0; cf < 4; cf++) {
        const short* kb_ = kh + (size_t)((kvn >> 4) + cf) * 1024 + lane * 8;
        kfr[cf][0] = *(const bf16x8*)kb_;
        kfr[cf][1] = *(const bf16x8*)(kb_ + 512);
      }
    }

    // V^T loads (current tile, contiguous); consumed in PV
    bf16x8 vb[4][2];
#pragma unroll
    for (int df = 0; df < 4; df++)
#pragma unroll
      for (int kf = 0; kf < 2; kf++)
        vb[df][kf] = *(const bf16x8*)(vh + df * 32768 + (kv0 >> 3) * 128 + kf * 512 + lane * 8);

    bool nm = (kv0 + 63 > qw);

    // ---- rf=0: mask + softmax + pack; then PV0 (soft1 below overlaps PV0) ----
    if (nm) {
#pragma unroll
      for (int cf = 0; cf < 4; cf++)
#pragma unroll
        for (int r = 0; r < 4; r++) {
          int kvi = kv0 + cf * 16 + l4 * 4 + r;
          if (kvi > qw + r16) sf[0][cf][r] = -1e30f;
        }
    }
    {
      float rs = 0.f;
#pragma unroll
      for (int cf = 0; cf < 4; cf++) {
        float p0 = __builtin_amdgcn_exp2f(sf[0][cf][0]);
        float p1 = __builtin_amdgcn_exp2f(sf[0][cf][1]);
        float p2v = __builtin_amdgcn_exp2f(sf[0][cf][2]);
        float p3 = __builtin_amdgcn_exp2f(sf[0][cf][3]);
        rs += (p0 + p1) + (p2v + p3);
        unsigned w0 = cvt_pk_bf16(p0, p1);
        unsigned w1 = cvt_pk_bf16(p2v, p3);
        *(int2*)&sh.p2[wid][0][r16][cf * 16 + l4 * 4] = make_int2((int)w0, (int)w1);
      }
      l0 += rs;
    }
#pragma unroll
    for (int kf = 0; kf < 2; kf++) {
      bf16x8 pa = *(const bf16x8*)&sh.p2[wid][0][r16][kf * 32 + l4 * 8];
#pragma unroll
      for (int df = 0; df < 4; df++)
        of[0][df] = __builtin_amdgcn_mfma_f32_16x16x32_bf16(vb[df][kf], pa, of[0][df], 0, 0, 0);
    }

    // ---- rf=1: mask + softmax + pack; then PV1 ----
    if (nm) {
#pragma unroll
      for (int cf = 0; cf < 4; cf++)
#pragma unroll
        for (int r = 0; r < 4; r++) {
          int kvi = kv0 + cf * 16 + l4 * 4 + r;
          if (kvi > qw + 16 + r16) sf[1][cf][r] = -1e30f;
        }
    }
    {
      float rs = 0.f;
#pragma unroll
      for (int cf = 0; cf < 4; cf++) {
        float p0 = __builtin_amdgcn_exp2f(sf[1][cf][0]);
        float p1 = __builtin_amdgcn_exp2f(sf[1][cf][1]);
        float p2v = __builtin_amdgcn_exp2f(sf[1][cf][2]);
        float p3 = __builtin_amdgcn_exp2f(sf[1][cf][3]);
        rs += (p0 + p1) + (p2v + p3);
        unsigned w0 = cvt_pk_bf16(p0, p1);
        unsigned w1 = cvt_pk_bf16(p2v, p3);
        *(int2*)&sh.p2[wid][1][r16][cf * 16 + l4 * 4] = make_int2((int)w0, (int)w1);
      }
      l1 += rs;
    }
#pragma unroll
    for (int kf = 0; kf < 2; kf++) {
      bf16x8 pa = *(const bf16x8*)&sh.p2[wid][1][r16][kf * 32 + l4 * 8];
#pragma unroll
      for (int df = 0; df < 4; df++)
        of[1][df] = __builtin_amdgcn_mfma_f32_16x16x32_bf16(vb[df][kf], pa, of[1][df], 0, 0, 0);
    }
  }

  // one-time l reduction across the 4 l4-groups (per q-column r16)
  l0 += __shfl_xor(l0, 16); l0 += __shfl_xor(l0, 32);
  l1 += __shfl_xor(l1, 16); l1 += __shfl_xor(l1, 32);

  // ---- merge the 4 KV-split partials in TWO df-passes (halved LDS) ----
  __syncthreads();                           // everyone done with p2
  if (l4 == 0) {
    sh.mg.ol[wid][r16] = l0;
    sh.mg.ol[wid][16 + r16] = l1;
  }
#pragma unroll
  for (int pass = 0; pass < 2; ++pass) {
#pragma unroll
    for (int rf = 0; rf < 2; rf++)
#pragma unroll
      for (int dfp = 0; dfp < 2; dfp++)
        sh.mg.obuf[wid][rf][dfp][lane] = of[rf][2 * pass + dfp];
    __syncthreads();
    {
      int mrf = wid >> 1, mdfp = wid & 1, mdf = 2 * pass + mdfp;
      int row = mrf * 16 + r16;
      float lst = sh.mg.ol[0][row] + sh.mg.ol[1][row] + sh.mg.ol[2][row] + sh.mg.ol[3][row];
      float rinv = 1.0f / lst;
      f32x4 o0 = sh.mg.obuf[0][mrf][mdfp][lane];
      f32x4 o1 = sh.mg.obuf[1][mrf][mdfp][lane];
      f32x4 o2 = sh.mg.obuf[2][mrf][mdfp][lane];
      f32x4 o3 = sh.mg.obuf[3][mrf][mdfp][lane];
      float v0 = (o0[0] + o1[0] + o2[0] + o3[0]) * rinv;
      float v1 = (o0[1] + o1[1] + o2[1] + o3[1]) * rinv;
      float v2 = (o0[2] + o1[2] + o2[2] + o3[2]) * rinv;
      float v3 = (o0[3] + o1[3] + o2[3] + o3[3]) * rinv;
      int t = qw + mrf * 16 + r16;
      *(int2*)&O[(size_t)(b * NT + t) * ND + h * 64 + mdf * 16 + l4 * 4] =
          make_int2((int)cvt_pk_bf16(v0, v1), (int)cvt_pk_bf16(v2, v3));
    }
    __syncthreads();                         // pass reads done before next pass writes
  }
}

extern "C" void kernel_launch(void* const* d_in, const int* in_sizes, int n_in,
                              void* d_out, int out_size, void* d_ws, size_t ws_size,
                              hipStream_t stream)
{
  const float* Q  = (const float*)d_in[0];
  const float* Ki = (const float*)d_in[1];
  const float* V  = (const float*)d_in[2];
  // d_in[3] = causal mask (tril) -- handled analytically
  const float* Wq = (const float*)d_in[4];  const float* bq = (const float*)d_in[5];
  const float* Wk = (const float*)d_in[6];  const float* bk = (const float*)d_in[7];
  const float* Wv = (const float*)d_in[8];  const float* bv = (const float*)d_in[9];
  const float* Wo = (const float*)d_in[10]; const float* bo = (const float*)d_in[11];

  short* ws = (short*)d_ws;
  const size_t M4 = (size_t)4 * 1024 * 1024;       // elems in one [B,T,D]
  short* Qb  = ws;                                  // bf16 casts of inputs
  short* Kb  = ws + M4;
  short* Vb  = ws + 2 * M4;
  short* qp  = ws + 3 * M4;                         // projected q, [B,H,T,DK] (pre-scaled)
  short* kp  = ws + 4 * M4;                         // projected k, fragment order
  short* vtp = ws + 5 * M4;                         // projected V^T, fragment order
  short* Wqt = ws + 6 * M4;                         // transposed bf16 weights [N,K]
  short* Wkt = Wqt + 1024 * 1024;
  short* Wvt = Wkt + 1024 * 1024;
  short* Wot = Wvt + 1024 * 1024;
  short* Obuf = Qb;                                 // attention out reuses Qb slot

  prep_kernel<<<10240, 256, 0, stream>>>(Q, Ki, V, Qb, Kb, Vb,
                                         Wq, Wk, Wv, Wo, Wqt, Wkt, Wvt, Wot);

  gemm_bt<0><<<1536, 256, 0, stream>>>(Qb, Kb, Vb, Wqt, Wkt, Wvt,
                                       bq, bk, bv, qp, kp, vtp);
  attn_kernel<<<2048, 256, 0, stream>>>(qp, kp, vtp, Obuf);
  gemm_bt<1><<<512, 256, 0, stream>>>(Obuf, Obuf, Obuf, Wot, Wot, Wot,
                                      bo, bo, bo, d_out, d_out, d_out);
}

// Round 24
// 111.679 us; speedup vs baseline: 1.0816x; 1.0816x over previous
//
#include <hip/hip_runtime.h>
#include <hip/hip_bf16.h>

#define NB 2
#define NT 2048
#define ND 1024
#define NH 16
#define NDK 64

typedef __attribute__((ext_vector_type(8))) short bf16x8;
typedef __attribute__((ext_vector_type(4))) float f32x4;

#define VMCNT0 asm volatile("s_waitcnt vmcnt(0)" ::: "memory")
#define VMCNT3 asm volatile("s_waitcnt vmcnt(3)" ::: "memory")
#define VMCNT4 asm volatile("s_waitcnt vmcnt(4)" ::: "memory")

static __device__ __forceinline__ short f2bf(float f) {
  union { float f; unsigned u; } c; c.f = f;
  unsigned u = c.u;
  u += 0x7FFF + ((u >> 16) & 1);   // round-to-nearest-even
  return (short)(u >> 16);
}

// packed RNE f32x2 -> bf16x2 (1 instr)
static __device__ __forceinline__ unsigned cvt_pk_bf16(float lo, float hi) {
  unsigned r;
  asm("v_cvt_pk_bf16_f32 %0, %1, %2" : "=v"(r) : "v"(lo), "v"(hi));
  return r;
}

static __device__ __forceinline__ void gload16(const void* g, void* l) {
  __builtin_amdgcn_global_load_lds((const __attribute__((address_space(1))) void*)g,
                                   (__attribute__((address_space(3))) void*)l, 16, 0, 0);
}

// ---------------- prep: fp32->bf16 cast (3 tensors) + weight transpose (4), one launch ----
__global__ void prep_kernel(const float* __restrict__ Q, const float* __restrict__ Ki,
                            const float* __restrict__ V,
                            short* __restrict__ Qb, short* __restrict__ Kb, short* __restrict__ Vb,
                            const float* __restrict__ W0, const float* __restrict__ W1,
                            const float* __restrict__ W2, const float* __restrict__ W3,
                            short* __restrict__ T0, short* __restrict__ T1,
                            short* __restrict__ T2, short* __restrict__ T3) {
  __shared__ float t[32][33];
  int d = blockIdx.x, tid = threadIdx.x;
  if (d < 6144) {                             // cast part: 2048 blocks per tensor
    int z = d >> 11;
    int i = (d & 2047) * 256 + tid;
    const float* src = z == 0 ? Q : (z == 1 ? Ki : V);
    short* dst       = z == 0 ? Qb : (z == 1 ? Kb : Vb);
    const float4* s4 = (const float4*)src + (size_t)i * 2;
    float4 a = s4[0], b = s4[1];
    bf16x8 o;
    o[0] = f2bf(a.x); o[1] = f2bf(a.y); o[2] = f2bf(a.z); o[3] = f2bf(a.w);
    o[4] = f2bf(b.x); o[5] = f2bf(b.y); o[6] = f2bf(b.z); o[7] = f2bf(b.w);
    *((bf16x8*)dst + i) = o;
  } else {                                    // wtrans part: 1024 blocks per weight
    int dd = d - 6144;
    int z = dd >> 10;
    int rem = dd & 1023;
    const float* W = z == 0 ? W0 : (z == 1 ? W1 : (z == 2 ? W2 : W3));
    short* Wt      = z == 0 ? T0 : (z == 1 ? T1 : (z == 2 ? T2 : T3));
    int n0 = (rem & 31) * 32, k0 = (rem >> 5) * 32;
    int tx = tid & 31, ty = tid >> 5;         // (32,8)
    for (int i = ty; i < 32; i += 8) t[i][tx] = W[(size_t)(k0 + i) * ND + n0 + tx];
    __syncthreads();
    for (int i = ty; i < 32; i += 8) Wt[(size_t)(n0 + i) * ND + k0 + tx] = f2bf(t[tx][i]);
  }
}

// ---------------- GEMM: C[M,N] = A[M,K] * Wt[N,K]^T + bias ----------------
// 128xBN tile, BK=32, 4 waves, 16x16x32 bf16 MFMA. Triple-buffered LDS with
// counted vmcnt + raw s_barrier. 1D grid with XCD-aware swizzle.
// LDS-transpose epilogue: vector stores (int2 / float4).
// MODE 0 (BN=128, projections): z=0 -> q (PRE-SCALED by 0.125*log2e) [B,H,T,DK];
//   z=1 -> k fragment order [bh][t>>4][dk>>3][t&15][dk&7];
//   z=2 -> V^T fragment order [bh][dk>>4][t>>3][dk&15][t&7].
// MODE 1 (BN=64): fp32 out [M,N].
template <int MODE, int BN>
__global__ __launch_bounds__(256, 3) void gemm_bt(
    const short* __restrict__ A0, const short* __restrict__ A1, const short* __restrict__ A2,
    const short* __restrict__ W0, const short* __restrict__ W1, const short* __restrict__ W2,
    const float* __restrict__ b0, const float* __restrict__ b1, const float* __restrict__ b2,
    void* o0, void* o1, void* o2)
{
  constexpr int K = ND;
  constexpr int NK = K / 32;
  constexpr int NI = BN / 32;
  constexpr int NNB = ND / BN;
  constexpr int NZ = (MODE == 0) ? 3 : 1;
  constexpr int NWPX = NZ * 32 * NNB / 8;
  __shared__ short As[3][128 * 32];
  __shared__ short Bs[3][BN * 32];

  int d = blockIdx.x;
  int work = (d & 7) * NWPX + (d >> 3);
  int z = work / (32 * NNB);
  int rem = work % (32 * NNB);
  int m0 = (rem / NNB) * 128, n0 = (rem % NNB) * BN;

  const short* A    = z == 0 ? A0 : (z == 1 ? A1 : A2);
  const short* Wt   = z == 0 ? W0 : (z == 1 ? W1 : W2);
  const float* bias = z == 0 ? b0 : (z == 1 ? b1 : b2);
  void* out         = z == 0 ? o0 : (z == 1 ? o1 : o2);
  float scl = (MODE == 0 && z == 0) ? 0.18033688011112042f : 1.0f;

  int tid = threadIdx.x, wid = tid >> 6, lane = tid & 63;
  int wr = wid >> 1, wc = wid & 1;
  int r16 = lane & 15, l4 = lane >> 4;

  auto stage = [&](int buf, int kt) {
    int row = (lane >> 2);
    int c8 = (lane & 3) * 8;
    {
      int rbase = wid * 32;
      const short* ga = A + (size_t)(m0 + rbase + row) * K + kt * 32 + c8;
      gload16(ga,          &As[buf][rbase * 32]);
      gload16(ga + 16 * K, &As[buf][(rbase + 16) * 32]);
    }
    if constexpr (BN == 128) {
      int rbase = wid * 32;
      const short* gb = Wt + (size_t)(n0 + rbase + row) * K + kt * 32 + c8;
      gload16(gb,          &Bs[buf][rbase * 32]);
      gload16(gb + 16 * K, &Bs[buf][(rbase + 16) * 32]);
    } else {
      int rbase = wid * 16;
      const short* gb = Wt + (size_t)(n0 + rbase + row) * K + kt * 32 + c8;
      gload16(gb,          &Bs[buf][rbase * 32]);
    }
  };

  f32x4 acc[4][NI] = {};
  stage(0, 0);
  stage(1, 1);

  int cur = 0;
  for (int kt = 0; kt < NK; ++kt) {
    if (kt + 1 < NK) {
      if constexpr (BN == 128) VMCNT4; else VMCNT3;
    } else {
      VMCNT0;
    }
    __builtin_amdgcn_s_barrier();            // raw: no compiler vmcnt(0) drain
    if (kt + 2 < NK) {
      int nb_ = cur + 2; if (nb_ >= 3) nb_ -= 3;
      stage(nb_, kt + 2);
    }
    bf16x8 af[4], bfv[NI];
    int kk = l4 * 8;
#pragma unroll
    for (int mi = 0; mi < 4; mi++)
      af[mi] = *(const bf16x8*)&As[cur][(wr * 64 + mi * 16 + r16) * 32 + kk];
#pragma unroll
    for (int ni = 0; ni < NI; ni++)
      bfv[ni] = *(const bf16x8*)&Bs[cur][(wc * (BN / 2) + ni * 16 + r16) * 32 + kk];
#pragma unroll
    for (int mi = 0; mi < 4; mi++)
#pragma unroll
      for (int ni = 0; ni < NI; ni++)
        acc[mi][ni] = __builtin_amdgcn_mfma_f32_16x16x32_bf16(af[mi], bfv[ni], acc[mi][ni], 0, 0, 0);
    cur = cur + 1; if (cur >= 3) cur = 0;
  }

  int mb = m0 + wr * 64, nb = n0 + wc * (BN / 2);

  if constexpr (MODE == 0) {
    if (z == 2) {
#pragma unroll
      for (int mi = 0; mi < 4; mi++)
#pragma unroll
        for (int ni = 0; ni < NI; ni++) {
          int n = nb + ni * 16 + r16;
          float bv = bias[n];
          int h = n >> 6, dk = n & 63;
          int m0_ = mb + mi * 16 + l4 * 4;
          int bI = m0_ >> 11, t0 = m0_ & (NT - 1);
          int bh = bI * NH + h;
          short4 s4;
          s4.x = f2bf(acc[mi][ni][0] + bv);
          s4.y = f2bf(acc[mi][ni][1] + bv);
          s4.z = f2bf(acc[mi][ni][2] + bv);
          s4.w = f2bf(acc[mi][ni][3] + bv);
          *(short4*)&((short*)out)[(size_t)bh * 131072 + (dk >> 4) * 32768 +
                                   (t0 >> 3) * 128 + (dk & 15) * 8 + (t0 & 7)] = s4;
        }
      return;
    }
  }

  // ---- LDS-transpose epilogue (z=0, z=1, MODE1) ----
  __syncthreads();
  float* scr = (float*)&As[0][0] + wid * 320;  // per-wave [16][20] f32
#pragma unroll
  for (int mi = 0; mi < 4; mi++)
#pragma unroll
    for (int ni = 0; ni < NI; ni++) {
#pragma unroll
      for (int r = 0; r < 4; r++)
        scr[(l4 * 4 + r) * 20 + r16] = acc[mi][ni][r];
      float4 tv = *(float4*)&scr[r16 * 20 + l4 * 4];
      int n0q = nb + ni * 16 + l4 * 4;
      float4 bv4 = *(const float4*)&bias[n0q];
      float v0 = tv.x + bv4.x, v1 = tv.y + bv4.y;
      float v2 = tv.z + bv4.z, v3 = tv.w + bv4.w;
      int m = mb + mi * 16 + r16;
      if constexpr (MODE == 0) {
        int bI = m >> 11, t = m & (NT - 1);
        if (z == 0) {
          int h = n0q >> 6, dk = n0q & 63;
          *(int2*)&((short*)out)[((((size_t)bI * NH + h) * NT + t) << 6) + dk] =
              make_int2((int)cvt_pk_bf16(v0 * scl, v1 * scl),
                        (int)cvt_pk_bf16(v2 * scl, v3 * scl));
        } else {
          int bh = bI * NH + (n0q >> 6);
          int dk = n0q & 63;
          *(int2*)&((short*)out)[(size_t)bh * 131072 + (t >> 4) * 1024 +
                                 (dk >> 3) * 128 + (t & 15) * 8 + (dk & 7)] =
              make_int2((int)cvt_pk_bf16(v0, v1), (int)cvt_pk_bf16(v2, v3));
        }
      } else {
        *(float4*)&((float*)out)[(size_t)m * ND + n0q] = make_float4(v0, v1, v2, v3);
      }
    }
}

// ---------------- flash attention v11 (best measured: ~40.2 us) ----------
// 2048 blocks x 4 waves, KV-split-4, fragment-contiguous K/V, K rotate-prefetch,
// max-free exp2 softmax, O^T orientation, rf-staggered, two-pass merge.
__global__ __launch_bounds__(256) void attn_kernel(
    const short* __restrict__ q, const short* __restrict__ k, const short* __restrict__ vt,
    short* __restrict__ O)
{
  struct SH {
    union {
      short p2[4][2][16][72];                // per-wave P tile (loop phase), 18432 B
      struct {
        f32x4 obuf[4][2][2][64];             // [wave][rf][dfp][lane], 16384 B
        float ol[4][32];                     // [wave][qrow]
      } mg;                                  // merge phase (two df-passes)
    };
  };
  __shared__ SH sh;

  int d = blockIdx.x;                        // 2048 blocks
  int xcd = d & 7, jj = d >> 3;              // jj in 0..255
  int bh = xcd * 4 + (jj >> 6);              // 4 (b,h) per XCD for L2 locality
  int qg = 63 - (jj & 63);                   // long q-groups dispatch first
  int b = bh >> 4, h = bh & 15;
  int tid = threadIdx.x, wid = tid >> 6, lane = tid & 63;
  int r16 = lane & 15, l4 = lane >> 4;
  size_t hb = (size_t)bh * NT * NDK;
  const short* qh = q + hb;
  const short* kh = k + hb;                  // fragment order [t>>4][dk>>3][t&15][dk&7]
  const short* vh = vt + hb;                 // fragment order [dk>>4][t>>3][dk&15][t&7]
  int qw = qg * 32;                          // this block's 32 q-rows

  // Q fragments (B-operand): same for all 4 waves
  bf16x8 qa[2][2];
#pragma unroll
  for (int rf = 0; rf < 2; rf++)
#pragma unroll
    for (int kf = 0; kf < 2; kf++)
      qa[rf][kf] = *(const bf16x8*)(qh + (size_t)(qw + rf * 16 + r16) * NDK + kf * 32 + l4 * 8);

  f32x4 of[2][4] = {};
  float l0 = 0.f, l1 = 0.f;

  int nt = (qw + 95) >> 6;                   // KV tiles covering kv <= qw+31

  // preload K fragments for this wave's first tile (rotate-register pipeline)
  bf16x8 kfr[4][2];
  if (wid < nt) {
#pragma unroll
    for (int cf = 0; cf < 4; cf++) {
      const short* kb_ = kh + (size_t)((wid * 64 >> 4) + cf) * 1024 + lane * 8;
      kfr[cf][0] = *(const bf16x8*)kb_;
      kfr[cf][1] = *(const bf16x8*)(kb_ + 512);
    }
  }

  for (int kt = wid; kt < nt; kt += 4) {
    int kv0 = kt * 64;
    f32x4 sf[2][4] = {};

    // QK rf=0
#pragma unroll
    for (int cf = 0; cf < 4; cf++) {
      sf[0][cf] = __builtin_amdgcn_mfma_f32_16x16x32_bf16(kfr[cf][0], qa[0][0], sf[0][cf], 0, 0, 0);
      sf[0][cf] = __builtin_amdgcn_mfma_f32_16x16x32_bf16(kfr[cf][1], qa[0][1], sf[0][cf], 0, 0, 0);
    }
    // QK rf=1
#pragma unroll
    for (int cf = 0; cf < 4; cf++) {
      sf[1][cf] = __builtin_amdgcn_mfma_f32_16x16x32_bf16(kfr[cf][0], qa[1][0], sf[1][cf], 0, 0, 0);
      sf[1][cf] = __builtin_amdgcn_mfma_f32_16x16x32_bf16(kfr[cf][1], qa[1][1], sf[1][cf], 0, 0, 0);
    }

    // prefetch K for tile kt+4 into the same registers (clamped past end);
    // latency hides under the softmax/PV below
    {
      int ktn = (kt + 4 < nt) ? kt + 4 : kt;
      int kvn = ktn * 64;
#pragma unroll
      for (int cf = 0; cf < 4; cf++) {
        const short* kb_ = kh + (size_t)((kvn >> 4) + cf) * 1024 + lane * 8;
        kfr[cf][0] = *(const bf16x8*)kb_;
        kfr[cf][1] = *(const bf16x8*)(kb_ + 512);
      }
    }

    // V^T loads (current tile, contiguous); consumed in PV
    bf16x8 vb[4][2];
#pragma unroll
    for (int df = 0; df < 4; df++)
#pragma unroll
      for (int kf = 0; kf < 2; kf++)
        vb[df][kf] = *(const bf16x8*)(vh + df * 32768 + (kv0 >> 3) * 128 + kf * 512 + lane * 8);

    bool nm = (kv0 + 63 > qw);

    // ---- rf=0: mask + softmax + pack; then PV0 (soft1 below overlaps PV0) ----
    if (nm) {
#pragma unroll
      for (int cf = 0; cf < 4; cf++)
#pragma unroll
        for (int r = 0; r < 4; r++) {
          int kvi = kv0 + cf * 16 + l4 * 4 + r;
          if (kvi > qw + r16) sf[0][cf][r] = -1e30f;
        }
    }
    {
      float rs = 0.f;
#pragma unroll
      for (int cf = 0; cf < 4; cf++) {
        float p0 = __builtin_amdgcn_exp2f(sf[0][cf][0]);
        float p1 = __builtin_amdgcn_exp2f(sf[0][cf][1]);
        float p2v = __builtin_amdgcn_exp2f(sf[0][cf][2]);
        float p3 = __builtin_amdgcn_exp2f(sf[0][cf][3]);
        rs += (p0 + p1) + (p2v + p3);
        unsigned w0 = cvt_pk_bf16(p0, p1);
        unsigned w1 = cvt_pk_bf16(p2v, p3);
        *(int2*)&sh.p2[wid][0][r16][cf * 16 + l4 * 4] = make_int2((int)w0, (int)w1);
      }
      l0 += rs;
    }
#pragma unroll
    for (int kf = 0; kf < 2; kf++) {
      bf16x8 pa = *(const bf16x8*)&sh.p2[wid][0][r16][kf * 32 + l4 * 8];
#pragma unroll
      for (int df = 0; df < 4; df++)
        of[0][df] = __builtin_amdgcn_mfma_f32_16x16x32_bf16(vb[df][kf], pa, of[0][df], 0, 0, 0);
    }

    // ---- rf=1: mask + softmax + pack; then PV1 ----
    if (nm) {
#pragma unroll
      for (int cf = 0; cf < 4; cf++)
#pragma unroll
        for (int r = 0; r < 4; r++) {
          int kvi = kv0 + cf * 16 + l4 * 4 + r;
          if (kvi > qw + 16 + r16) sf[1][cf][r] = -1e30f;
        }
    }
    {
      float rs = 0.f;
#pragma unroll
      for (int cf = 0; cf < 4; cf++) {
        float p0 = __builtin_amdgcn_exp2f(sf[1][cf][0]);
        float p1 = __builtin_amdgcn_exp2f(sf[1][cf][1]);
        float p2v = __builtin_amdgcn_exp2f(sf[1][cf][2]);
        float p3 = __builtin_amdgcn_exp2f(sf[1][cf][3]);
        rs += (p0 + p1) + (p2v + p3);
        unsigned w0 = cvt_pk_bf16(p0, p1);
        unsigned w1 = cvt_pk_bf16(p2v, p3);
        *(int2*)&sh.p2[wid][1][r16][cf * 16 + l4 * 4] = make_int2((int)w0, (int)w1);
      }
      l1 += rs;
    }
#pragma unroll
    for (int kf = 0; kf < 2; kf++) {
      bf16x8 pa = *(const bf16x8*)&sh.p2[wid][1][r16][kf * 32 + l4 * 8];
#pragma unroll
      for (int df = 0; df < 4; df++)
        of[1][df] = __builtin_amdgcn_mfma_f32_16x16x32_bf16(vb[df][kf], pa, of[1][df], 0, 0, 0);
    }
  }

  // one-time l reduction across the 4 l4-groups (per q-column r16)
  l0 += __shfl_xor(l0, 16); l0 += __shfl_xor(l0, 32);
  l1 += __shfl_xor(l1, 16); l1 += __shfl_xor(l1, 32);

  // ---- merge the 4 KV-split partials in TWO df-passes (halved LDS) ----
  __syncthreads();                           // everyone done with p2
  if (l4 == 0) {
    sh.mg.ol[wid][r16] = l0;
    sh.mg.ol[wid][16 + r16] = l1;
  }
#pragma unroll
  for (int pass = 0; pass < 2; ++pass) {
#pragma unroll
    for (int rf = 0; rf < 2; rf++)
#pragma unroll
      for (int dfp = 0; dfp < 2; dfp++)
        sh.mg.obuf[wid][rf][dfp][lane] = of[rf][2 * pass + dfp];
    __syncthreads();
    {
      int mrf = wid >> 1, mdfp = wid & 1, mdf = 2 * pass + mdfp;
      int row = mrf * 16 + r16;
      float lst = sh.mg.ol[0][row] + sh.mg.ol[1][row] + sh.mg.ol[2][row] + sh.mg.ol[3][row];
      float rinv = 1.0f / lst;
      f32x4 o0 = sh.mg.obuf[0][mrf][mdfp][lane];
      f32x4 o1 = sh.mg.obuf[1][mrf][mdfp][lane];
      f32x4 o2 = sh.mg.obuf[2][mrf][mdfp][lane];
      f32x4 o3 = sh.mg.obuf[3][mrf][mdfp][lane];
      float v0 = (o0[0] + o1[0] + o2[0] + o3[0]) * rinv;
      float v1 = (o0[1] + o1[1] + o2[1] + o3[1]) * rinv;
      float v2 = (o0[2] + o1[2] + o2[2] + o3[2]) * rinv;
      float v3 = (o0[3] + o1[3] + o2[3] + o3[3]) * rinv;
      int t = qw + mrf * 16 + r16;
      *(int2*)&O[(size_t)(b * NT + t) * ND + h * 64 + mdf * 16 + l4 * 4] =
          make_int2((int)cvt_pk_bf16(v0, v1), (int)cvt_pk_bf16(v2, v3));
    }
    __syncthreads();                         // pass reads done before next pass writes
  }
}

extern "C" void kernel_launch(void* const* d_in, const int* in_sizes, int n_in,
                              void* d_out, int out_size, void* d_ws, size_t ws_size,
                              hipStream_t stream)
{
  const float* Q  = (const float*)d_in[0];
  const float* Ki = (const float*)d_in[1];
  const float* V  = (const float*)d_in[2];
  // d_in[3] = causal mask (tril) -- handled analytically
  const float* Wq = (const float*)d_in[4];  const float* bq = (const float*)d_in[5];
  const float* Wk = (const float*)d_in[6];  const float* bk = (const float*)d_in[7];
  const float* Wv = (const float*)d_in[8];  const float* bv = (const float*)d_in[9];
  const float* Wo = (const float*)d_in[10]; const float* bo = (const float*)d_in[11];

  short* ws = (short*)d_ws;
  const size_t M4 = (size_t)4 * 1024 * 1024;       // elems in one [B,T,D]
  short* Qb  = ws;                                  // bf16 casts of inputs
  short* Kb  = ws + M4;
  short* Vb  = ws + 2 * M4;
  short* qp  = ws + 3 * M4;                         // projected q, [B,H,T,DK] (pre-scaled)
  short* kp  = ws + 4 * M4;                         // projected k, fragment order
  short* vtp = ws + 5 * M4;                         // projected V^T, fragment order
  short* Wqt = ws + 6 * M4;                         // transposed bf16 weights [N,K]
  short* Wkt = Wqt + 1024 * 1024;
  short* Wvt = Wkt + 1024 * 1024;
  short* Wot = Wvt + 1024 * 1024;
  short* Obuf = Qb;                                 // attention out reuses Qb slot

  prep_kernel<<<10240, 256, 0, stream>>>(Q, Ki, V, Qb, Kb, Vb,
                                         Wq, Wk, Wv, Wo, Wqt, Wkt, Wvt, Wot);

  gemm_bt<0, 128><<<768, 256, 0, stream>>>(Qb, Kb, Vb, Wqt, Wkt, Wvt,
                                           bq, bk, bv, qp, kp, vtp);
  attn_kernel<<<2048, 256, 0, stream>>>(qp, kp, vtp, Obuf);
  gemm_bt<1, 64><<<512, 256, 0, stream>>>(Obuf, Obuf, Obuf, Wot, Wot, Wot,
                                          bo, bo, bo, d_out, d_out, d_out);
}